// Round 6
// baseline (17560.716 us; speedup 1.0000x reference)
//
#include <hip/hip_runtime.h>
#include <hip/hip_bf16.h>

typedef __bf16 bf16x8 __attribute__((ext_vector_type(8)));
typedef float f32x4 __attribute__((ext_vector_type(4)));
typedef unsigned long long u64;

#define B_ 128
#define S_ 1024
#define E_ 512
#define H_ 512
#define TOK 32            // tokens per group
#define KROWS 32          // gate-rows per wg: 2 cells x 4 gates x 4 columns
#define JW 4              // output columns per wg
#define WSTRIDE 1032      // 1024 + 8 bf16 pad
#define GSTR 33           // gbuf row stride (f32)
#define NGRP 4
#define WPG 128           // workgroups per group
#define FSTR 16           // flag stride in dwords (64B)
#define SMEM_BYTES (KROWS * WSTRIDE * 2 + KROWS * 4 + TOK * GSTR * 4)  // 70400

__device__ __forceinline__ float sigf(float x) { return 1.0f / (1.0f + __expf(-x)); }

__device__ __forceinline__ bf16x8 cvt8(float4 a, float4 b) {
    bf16x8 r;
    r[0] = (__bf16)a.x; r[1] = (__bf16)a.y; r[2] = (__bf16)a.z; r[3] = (__bf16)a.w;
    r[4] = (__bf16)b.x; r[5] = (__bf16)b.y; r[6] = (__bf16)b.z; r[7] = (__bf16)b.w;
    return r;
}

union bfpack { u64 q[2]; bf16x8 v; };
union bfbits { __hip_bfloat16 b; unsigned short s; };

__global__ void init_ws_kernel(unsigned int* bar) {
    // zero flags (NGRP*WPG) + go words (NGRP): 516*16 dwords
    for (int i = threadIdx.x; i < (NGRP * WPG + NGRP) * FSTR; i += 256) bar[i] = 0u;
}

__global__ void __launch_bounds__(256, 2)
lstm_kernel(const int* __restrict__ inp, const float* __restrict__ embed,
            const float* __restrict__ Wih, const float* __restrict__ Whh,
            const float* __restrict__ bih, const float* __restrict__ bhh,
            float* __restrict__ out, unsigned int* __restrict__ bar,
            __hip_bfloat16* __restrict__ hbuf)
{
    extern __shared__ char smem[];
    __hip_bfloat16* wbuf = (__hip_bfloat16*)smem;                 // [KROWS][WSTRIDE]
    float* bias_l = (float*)(smem + KROWS * WSTRIDE * 2);         // [32]
    float* gbuf   = bias_l + KROWS;                               // [TOK][GSTR]

    const int tid = threadIdx.x;
    const int bid = blockIdx.x;
    // co-residency mapping: CU c hosts bids {c, c+256} -> DIFFERENT groups
    const int grp = (bid + (bid >> 8)) & 3;
    const int r   = ((bid >> 8) << 6) + ((bid & 255) >> 2);   // 0..127 unique per group
    const int j0  = r * JW;

    // ---- stage weights (f32 -> bf16) into LDS. row n = cell*16 + gate*4 + jjj ----
    for (int it = tid; it < KROWS * 256; it += 256) {
        int n = it >> 8;
        int q = it & 255;          // float4 idx: 0..127 -> W_ih, 128..255 -> W_hh
        int cell = n >> 4, gate = (n >> 2) & 3, jjj = n & 3;
        size_t grow = (size_t)(cell * 2048 + gate * 512 + j0 + jjj);
        float4 v;
        int dstoff;
        if (q < 128) { v = ((const float4*)(Wih + grow * E_))[q];       dstoff = q * 4; }
        else         { v = ((const float4*)(Whh + grow * H_))[q - 128]; dstoff = 512 + (q - 128) * 4; }
        __hip_bfloat16* dst = wbuf + n * WSTRIDE + dstoff;
        dst[0] = __float2bfloat16(v.x); dst[1] = __float2bfloat16(v.y);
        dst[2] = __float2bfloat16(v.z); dst[3] = __float2bfloat16(v.w);
    }
    if (tid < KROWS) {
        int n = tid, cell = n >> 4, gate = (n >> 2) & 3, jjj = n & 3;
        size_t off = (size_t)cell * 2048 + gate * 512 + j0 + jjj;
        bias_l[tid] = bih[off] + bhh[off];
    }
    __syncthreads();

    // ---- MFMA task mapping: 4 waves = 2 token-tiles x 2 row-tiles ----
    const int lane = tid & 63, wid = tid >> 6;
    const int lm = lane & 15, quad = lane >> 4;
    const int mtile = wid & 1, ntile = wid >> 1;
    const int tokA = grp * TOK + mtile * 16 + lm;
    const float* xbase = embed + (size_t)tokA * S_ * E_ + quad * 8;
    const __hip_bfloat16* wx = wbuf + (ntile * 16 + lm) * WSTRIDE + quad * 8;
    const __hip_bfloat16* wh = wx + 512;
    const float bv = bias_l[ntile * 16 + lm];
    const __hip_bfloat16* hbA = hbuf + (size_t)tokA * H_ + quad * 8;

    // ---- epilogue mapping: thread (tid<128) owns (token b_loc, column jj) ----
    const int b_loc = tid >> 2, jj = tid & 3;
    const int b_glob = grp * TOK + b_loc;
    const int* inpp = inp + (size_t)b_glob * S_;
    float* outp = out + (size_t)b_glob * S_ * H_ + j0 + jj;
    __hip_bfloat16* hwp = hbuf + (size_t)b_glob * H_ + j0 + jj;
    float creg = 0.0f, hlast = 0.0f;

    // ---- leader-based barrier: 128 flags per group + one 'go' broadcast word ----
    volatile unsigned int* myflag = bar + (grp * WPG + r) * FSTR;
    volatile const unsigned int* pf0 = bar + (grp * WPG + lane) * FSTR;
    volatile const unsigned int* pf1 = pf0 + 64 * FSTR;
    volatile unsigned int* gop = bar + (NGRP * WPG + grp) * FSTR;

    // ---- prologue: acc_next = bias + Xproj(t=0); prefetch cell(0) ----
    f32x4 acc_next;
    {
        f32x4 ax = {bv, bv, bv, bv};
        const float* xp = xbase;
#pragma unroll
        for (int ks = 0; ks < 16; ++ks) {
            float4 f0 = *(const float4*)(xp + ks * 32);
            float4 f1 = *(const float4*)(xp + ks * 32 + 4);
            bf16x8 a = cvt8(f0, f1);
            bf16x8 b = *(const bf16x8*)(wx + ks * 32);
            ax = __builtin_amdgcn_mfma_f32_16x16x32_bf16(a, b, ax, 0, 0, 0);
        }
        acc_next = ax;
    }
    int cell_next = inpp[0];

    for (int t = 0; t < S_; ++t) {
        f32x4 acc = acc_next;
        const int cell_cur = cell_next;

        // h-projection, K = H = 512 (volatile bypass loads; h_0 = 0 -> skip at t=0)
        if (t > 0) {
            const volatile u64* hp = (const volatile u64*)(hbA + (size_t)(t & 1) * B_ * H_);
#pragma unroll
            for (int ks = 0; ks < 16; ++ks) {
                bfpack u;
                u.q[0] = hp[ks * 8];
                u.q[1] = hp[ks * 8 + 1];
                bf16x8 b = *(const bf16x8*)(wh + ks * 32);
                acc = __builtin_amdgcn_mfma_f32_16x16x32_bf16(u.v, b, acc, 0, 0, 0);
            }
        }

        // D[m][n]: token row = mtile*16 + quad*4 + reg, gate col = ntile*16 + lm
        {
            float* gp = gbuf + (mtile * 16 + quad * 4) * GSTR + ntile * 16 + lm;
            gp[0] = acc[0]; gp[GSTR] = acc[1]; gp[2 * GSTR] = acc[2]; gp[3 * GSTR] = acc[3];
        }
        __syncthreads();

        if (tid < 128) {
            int cell = cell_cur & 1;                     // vocab id % 2
            const float* gb = gbuf + b_loc * GSTR + cell * 16 + jj;
            float iv = gb[0], fv = gb[4], gv = gb[8], ov = gb[12];
            creg  = sigf(fv) * creg + sigf(iv) * tanhf(gv);
            hlast = sigf(ov) * tanhf(creg);
            bfbits cv; cv.b = __float2bfloat16(hlast);
            *(volatile unsigned short*)(hwp + (size_t)((t + 1) & 1) * B_ * H_) = cv.s;
        }

        // syncthreads drains vmcnt(0): h write-throughs acked before flag store
        __syncthreads();
        if (tid == 0) *myflag = (unsigned int)(t + 1);

        // ---- shadow region: hidden under the barrier wait ----
        if (tid < 128) outp[(size_t)t * H_] = hlast;
        {
            int tn = (t + 1 < S_) ? (t + 1) : (S_ - 1);
            cell_next = inpp[tn];
        }
        {
            f32x4 ax = {bv, bv, bv, bv};
            if (t + 1 < S_) {
                const float* xp = xbase + (size_t)(t + 1) * E_;
#pragma unroll
                for (int ks = 0; ks < 16; ++ks) {
                    float4 f0 = *(const float4*)(xp + ks * 32);
                    float4 f1 = *(const float4*)(xp + ks * 32 + 4);
                    bf16x8 a = cvt8(f0, f1);
                    bf16x8 b = *(const bf16x8*)(wx + ks * 32);
                    ax = __builtin_amdgcn_mfma_f32_16x16x32_bf16(a, b, ax, 0, 0, 0);
                }
            }
            acc_next = ax;
        }

        // ---- barrier: leader wg polls 128 flags then publishes 'go'; others poll go ----
        if (wid == 0) {
            const unsigned int tgt = (unsigned int)(t + 1);
            unsigned int guard = 0;
            if (r == 0) {
                while (!__all((int)(*pf0 >= tgt) & (int)(*pf1 >= tgt))) {
                    __builtin_amdgcn_s_sleep(2);
                    if (++guard > 0x02000000u) break;   // tripwire
                }
                if (lane == 0) *gop = tgt;
            } else {
                while (*gop < tgt) {
                    __builtin_amdgcn_s_sleep(2);
                    if (++guard > 0x02000000u) break;   // tripwire
                }
            }
        }
        __syncthreads();
    }

    if (tid < 128) {
        size_t base = (size_t)B_ * S_ * H_;
        out[base + (size_t)b_glob * H_ + j0 + jj] = hlast;                    // h_last
        out[base + (size_t)B_ * H_ + (size_t)b_glob * H_ + j0 + jj] = creg;   // c_last
    }
}

extern "C" void kernel_launch(void* const* d_in, const int* in_sizes, int n_in,
                              void* d_out, int out_size, void* d_ws, size_t ws_size,
                              hipStream_t stream) {
    const int* inp     = (const int*)d_in[0];
    const float* embed = (const float*)d_in[1];
    const float* Wih   = (const float*)d_in[2];
    const float* Whh   = (const float*)d_in[3];
    const float* bih   = (const float*)d_in[4];
    const float* bhh   = (const float*)d_in[5];
    float* out         = (float*)d_out;

    unsigned int* bar    = (unsigned int*)d_ws;                        // 36 KB flag region
    __hip_bfloat16* hbuf = (__hip_bfloat16*)((char*)d_ws + 36864);     // 2 x B x H bf16 = 256 KB

    static_assert(SMEM_BYTES <= 80 * 1024, "LDS too big for 2 wgs/CU");
    hipFuncSetAttribute((const void*)lstm_kernel,
                        hipFuncAttributeMaxDynamicSharedMemorySize, SMEM_BYTES);

    hipLaunchKernelGGL(init_ws_kernel, dim3(1), dim3(256), 0, stream, bar);
    hipLaunchKernelGGL(lstm_kernel, dim3(512), dim3(256), SMEM_BYTES, stream,
                       inp, embed, Wih, Whh, bih, bhh, out, bar, hbuf);
}